// Round 4
// baseline (263.327 us; speedup 1.0000x reference)
//
#include <hip/hip_runtime.h>
#include <stdint.h>
#include <stddef.h>

#define B_ 8
#define L_ 2048
#define D_ 256
#define KSPLIT 4
#define KRANGE 512
#define KTILE 16
#define NITER 32
#define PSS 40

typedef __bf16 bf16x8 __attribute__((ext_vector_type(8)));
typedef float floatx4 __attribute__((ext_vector_type(4)));
typedef _Float16 half4_t __attribute__((ext_vector_type(4)));

__device__ __forceinline__ short f2bf(float f) {
    union { float f; uint32_t u; } v; v.f = f;
    return (short)((v.u + 0x8000u) >> 16);
}

__device__ __forceinline__ uint32_t pack2bf(float a, float b) {
    union { float f; uint32_t u; } x, y; x.f = a; y.f = b;
    return ((x.u + 0x8000u) >> 16) | ((y.u + 0x8000u) & 0xFFFF0000u);
}

__device__ __forceinline__ void async16(const void* g, void* l) {
    __builtin_amdgcn_global_load_lds(
        (__attribute__((address_space(1))) void*)g,
        (__attribute__((address_space(3))) void*)l,
        16, 0, 0);
}

// ---------------------------------------------------------------------------
// Fused q/k projection, double-buffered LDS: Out = bf16(X @ W^T + bias).
// ---------------------------------------------------------------------------
__global__ __launch_bounds__(256, 3) void proj_kernel(
    const float* __restrict__ Xq, const float* __restrict__ Xk,
    const float* __restrict__ Wq, const float* __restrict__ Wk,
    const float* __restrict__ bq, const float* __restrict__ bk,
    short* __restrict__ Oq, short* __restrict__ Ok)
{
    const float* X    = blockIdx.y ? Xk : Xq;
    const float* W    = blockIdx.y ? Wk : Wq;
    const float* bias = blockIdx.y ? bk : bq;
    short* Out        = blockIdx.y ? Ok : Oq;

    __shared__ uint32_t As[2][64 * 20];
    __shared__ uint32_t Ws[2][256 * 20];

    const int tid  = threadIdx.x;
    const int wid  = tid >> 6;
    const int lane = tid & 63;
    const int m16  = lane & 15;
    const int quad = lane >> 4;
    const int row0 = blockIdx.x * 64;
    const int ar = tid >> 2, cg = tid & 3;

    floatx4 acc[16];
    const floatx4 z4 = {0.f, 0.f, 0.f, 0.f};
#pragma unroll
    for (int i = 0; i < 16; i++) acc[i] = z4;

    {
        const float* srcA = X + (size_t)(row0 + ar) * D_ + cg * 8;
        float4 a = *(const float4*)srcA, b2 = *(const float4*)(srcA + 4);
        uint4 u; u.x = pack2bf(a.x, a.y); u.y = pack2bf(a.z, a.w);
        u.z = pack2bf(b2.x, b2.y); u.w = pack2bf(b2.z, b2.w);
        *(uint4*)&As[0][ar * 20 + cg * 4] = u;
#pragma unroll
        for (int p = 0; p < 4; p++) {
            const float* srcW = W + (size_t)(p * 64 + ar) * D_ + cg * 8;
            float4 wa = *(const float4*)srcW, wb = *(const float4*)(srcW + 4);
            uint4 w; w.x = pack2bf(wa.x, wa.y); w.y = pack2bf(wa.z, wa.w);
            w.z = pack2bf(wb.x, wb.y); w.w = pack2bf(wb.z, wb.w);
            *(uint4*)&Ws[0][(p * 64 + ar) * 20 + cg * 4] = w;
        }
    }
    __syncthreads();

    for (int kc = 0; kc < 8; kc++) {
        const int buf = kc & 1;
        float4 na, nb, nwa[4], nwb[4];
        if (kc < 7) {
            const int k1 = (kc + 1) * 32;
            const float* srcA = X + (size_t)(row0 + ar) * D_ + k1 + cg * 8;
            na = *(const float4*)srcA; nb = *(const float4*)(srcA + 4);
#pragma unroll
            for (int p = 0; p < 4; p++) {
                const float* srcW = W + (size_t)(p * 64 + ar) * D_ + k1 + cg * 8;
                nwa[p] = *(const float4*)srcW; nwb[p] = *(const float4*)(srcW + 4);
            }
        }
        bf16x8 af = *(const bf16x8*)&As[buf][(wid * 16 + m16) * 20 + quad * 4];
#pragma unroll
        for (int n = 0; n < 16; n++) {
            bf16x8 bfr = *(const bf16x8*)&Ws[buf][(n * 16 + m16) * 20 + quad * 4];
            acc[n] = __builtin_amdgcn_mfma_f32_16x16x32_bf16(af, bfr, acc[n], 0, 0, 0);
        }
        if (kc < 7) {
            uint4 u; u.x = pack2bf(na.x, na.y); u.y = pack2bf(na.z, na.w);
            u.z = pack2bf(nb.x, nb.y); u.w = pack2bf(nb.z, nb.w);
            *(uint4*)&As[buf ^ 1][ar * 20 + cg * 4] = u;
#pragma unroll
            for (int p = 0; p < 4; p++) {
                uint4 w; w.x = pack2bf(nwa[p].x, nwa[p].y); w.y = pack2bf(nwa[p].z, nwa[p].w);
                w.z = pack2bf(nwb[p].x, nwb[p].y); w.w = pack2bf(nwb[p].z, nwb[p].w);
                *(uint4*)&Ws[buf ^ 1][(p * 64 + ar) * 20 + cg * 4] = w;
            }
        }
        __syncthreads();
    }
#pragma unroll
    for (int n = 0; n < 16; n++) {
        const int col = n * 16 + m16;
        const float bv = bias[col];
#pragma unroll
        for (int r = 0; r < 4; r++) {
            const int row = row0 + wid * 16 + quad * 4 + r;
            Out[(size_t)row * D_ + col] = f2bf(acc[n][r] + bv);
        }
    }
}

// ---------------------------------------------------------------------------
// V transpose: Vt[b][d][l] = bf16(V[b][l][d]).
// ---------------------------------------------------------------------------
__global__ __launch_bounds__(256, 2) void vtrans_kernel(
    const float* __restrict__ V, short* __restrict__ Vt)
{
    __shared__ uint32_t T[256 * 20];
    const int tid = threadIdx.x;
    const int b  = blockIdx.y;
    const int l0 = blockIdx.x * 32;
    const int r2 = tid >> 4;
    const int dg = tid & 15;
    const int lp = r2 ^ ((dg & 3) << 2);
#pragma unroll
    for (int p = 0; p < 4; p++) {
        int d0 = (dg + p * 16) * 4;
        const float* src = V + ((size_t)b * L_ + l0 + r2 * 2) * D_ + d0;
        float4 e0 = *(const float4*)src;
        float4 e1 = *(const float4*)(src + D_);
        T[(d0 + 0) * 20 + lp] = pack2bf(e0.x, e1.x);
        T[(d0 + 1) * 20 + lp] = pack2bf(e0.y, e1.y);
        T[(d0 + 2) * 20 + lp] = pack2bf(e0.z, e1.z);
        T[(d0 + 3) * 20 + lp] = pack2bf(e0.w, e1.w);
    }
    __syncthreads();
#pragma unroll
    for (int p = 0; p < 4; p++) {
        int d = (tid >> 2) + p * 64;
        int c = tid & 3;
        int cp = c ^ ((d >> 2) & 3);
        uint4 u = *(const uint4*)&T[d * 20 + cp * 4];
        *(uint4*)(Vt + ((size_t)b * D_ + d) * L_ + l0 + c * 8) = u;
    }
}

// ---------------------------------------------------------------------------
// Flash attention: qtile 64, 16 q-rows/wave, KTILE=16, PV every 2 iters
// (K=32 contraction), 4 waves/SIMD, 4 blocks/CU (37 KB LDS, <=128 regs).
// ---------------------------------------------------------------------------
__global__ __launch_bounds__(256, 4) void flash_kernel(
    const short* __restrict__ Qb, const short* __restrict__ Kb,
    const short* __restrict__ Vt, const int* __restrict__ mask,
    float* __restrict__ Out, _Float16* __restrict__ Part,
    float* __restrict__ Lpart)
{
    __shared__ short Ks[2][KTILE * 256];   // 2 x 8 KB, dbuf
    __shared__ short Vs[256 * 32];         // 16 KB, single buffer (32-k period)
    __shared__ short Ps[4 * 16 * PSS];     // 5 KB

    const int tid  = threadIdx.x;
    const int wid  = tid >> 6;
    const int lane = tid & 63;
    const int m16  = lane & 15;
    const int quad = lane >> 4;
    const int b  = blockIdx.x;
    const int q0 = blockIdx.y * 64;
    const int z  = blockIdx.z;

    const short* kbase = Kb + ((size_t)b * L_ + z * KRANGE) * D_;
    const short* vbase = Vt + (size_t)b * D_ * L_ + z * KRANGE;
    const int*   mg    = mask + b * L_ + z * KRANGE;

    bf16x8 qf[8];
    {
        const short* qrow = Qb + ((size_t)b * L_ + q0 + wid * 16 + m16) * D_;
#pragma unroll
        for (int kk = 0; kk < 8; kk++)
            qf[kk] = *(const bf16x8*)(qrow + kk * 32 + quad * 8);
    }

    floatx4 o[16];
    const floatx4 z4 = {0.f, 0.f, 0.f, 0.f};
#pragma unroll
    for (int n = 0; n < 16; n++) o[n] = z4;
    float rsum[4] = {0.f, 0.f, 0.f, 0.f};

    auto stageK = [&](int t, int bufi) {
#pragma unroll
        for (int c = 0; c < 2; c++) {
            int rbase = wid * 4 + c * 2;
            int row = rbase + (lane >> 5);
            int g = (lane & 31) ^ (row & 7);
            async16(kbase + (size_t)(t * KTILE + row) * D_ + g * 8,
                    &Ks[bufi][rbase * 256]);
        }
    };
    auto stageV = [&](int P) {
#pragma unroll
        for (int c = 0; c < 4; c++) {
            int rbase = wid * 64 + c * 16;
            int d = rbase + (lane >> 2);
            int g = (lane & 3) ^ (d & 3) ^ ((d >> 2) & 3);
            async16(vbase + (size_t)d * L_ + P * 32 + g * 8, &Vs[rbase * 32]);
        }
    };

    stageK(0, 0);
    stageV(0);
    __builtin_amdgcn_s_waitcnt(0x0F70);  // vmcnt(0)
    __syncthreads();

    short* ps = Ps + wid * (16 * PSS);
    const float C2 = 0.09016844f;        // log2(e)/16

    for (int t = 0; t < NITER; t++) {
        const int buf = t & 1;
        if (t + 1 < NITER) stageK(t + 1, buf ^ 1);
        if (t > 0 && (t & 1) == 0) stageV(t >> 1);   // V(P) for period P=t/2

        // ---- QK(t): 16q x 16k, d=256 ----
        const short* kl = &Ks[buf][0];
        floatx4 s = z4;
#pragma unroll
        for (int kk = 0; kk < 8; kk++) {
            int cidx = (kk * 4 + quad) ^ (m16 & 7);
            bf16x8 kf = *(const bf16x8*)(kl + m16 * 256 + cidx * 8);
            s = __builtin_amdgcn_mfma_f32_16x16x32_bf16(qf[kk], kf, s, 0, 0, 0);
        }

        // ---- softmax: P = exp2(S*C2 + moff), write Ps phase (t&1) ----
        const int mv = mg[t * KTILE + m16];
        const float moff = mv ? 0.f : -1.0e30f;
        const int ph = (t & 1) * 16;
#pragma unroll
        for (int r = 0; r < 4; r++) {
            float p = exp2f(fmaf(s[r], C2, moff));
            rsum[r] += p;
            ps[(quad * 4 + r) * PSS + ph + m16] = f2bf(p);
        }

        // ---- PV on odd iters: 16q x 32k x 256d ----
        if (t & 1) {
            __builtin_amdgcn_s_waitcnt(0xC07F);  // lgkmcnt(0): Ps visible
            bf16x8 pf = *(const bf16x8*)(ps + m16 * PSS + quad * 8);
#pragma unroll
            for (int n = 0; n < 16; n++) {
                int d = n * 16 + m16;
                int cidx = quad ^ (d & 3) ^ ((d >> 2) & 3);
                bf16x8 vf = *(const bf16x8*)(Vs + d * 32 + cidx * 8);
                o[n] = __builtin_amdgcn_mfma_f32_16x16x32_bf16(pf, vf, o[n], 0, 0, 0);
            }
        }

        __builtin_amdgcn_s_waitcnt(0x0F70);  // vmcnt(0): staging landed
        __syncthreads();
    }

    // ---- row-sum reduce across 16 column-lanes ----
#pragma unroll
    for (int r = 0; r < 4; r++) {
        float x = rsum[r];
        x += __shfl_xor(x, 1, 16);
        x += __shfl_xor(x, 2, 16);
        x += __shfl_xor(x, 4, 16);
        x += __shfl_xor(x, 8, 16);
        rsum[r] = x;
    }

    const size_t BLD = (size_t)B_ * L_ * D_;
    const size_t rowbase = (size_t)b * L_ + q0 + wid * 16;
    if (z == 0) {
        float* po = Out + rowbase * D_;
#pragma unroll
        for (int n = 0; n < 16; n++)
#pragma unroll
            for (int r = 0; r < 4; r++)
                po[(size_t)(quad * 4 + r) * D_ + n * 16 + m16] = o[n][r];
    } else {
        _Float16* pp = Part + (size_t)(z - 1) * BLD + rowbase * D_;
#pragma unroll
        for (int n = 0; n < 16; n++)
#pragma unroll
            for (int r = 0; r < 4; r++)
                pp[(size_t)(quad * 4 + r) * D_ + n * 16 + m16] = (_Float16)o[n][r];
    }
    if (m16 == 0) {
#pragma unroll
        for (int r = 0; r < 4; r++)
            Lpart[(size_t)z * (B_ * L_) + rowbase + quad * 4 + r] = rsum[r];
    }
}

// ---------------------------------------------------------------------------
// Normalize: out = (P0_f32 + P1..3_f16) / (l0+l1+l2+l3)
// ---------------------------------------------------------------------------
__global__ __launch_bounds__(256) void norm_kernel(
    float* __restrict__ Out, const _Float16* __restrict__ Part,
    const float* __restrict__ Lpart)
{
    const int idx = blockIdx.x * 256 + threadIdx.x;
    const int row = idx >> 6;
    const int c   = (idx & 63) * 4;
    const size_t off = (size_t)row * D_ + c;
    const size_t BLD = (size_t)B_ * L_ * D_;
    float4 acc = *(float4*)(Out + off);
#pragma unroll
    for (int zz = 0; zz < 3; zz++) {
        half4_t h = *(const half4_t*)(Part + zz * BLD + off);
        acc.x += (float)h.x; acc.y += (float)h.y;
        acc.z += (float)h.z; acc.w += (float)h.w;
    }
    const int BL = B_ * L_;
    float l = Lpart[row] + Lpart[BL + row] + Lpart[2 * BL + row] + Lpart[3 * BL + row];
    float inv = 1.0f / l;
    acc.x *= inv; acc.y *= inv; acc.z *= inv; acc.w *= inv;
    *(float4*)(Out + off) = acc;
}

extern "C" void kernel_launch(void* const* d_in, const int* in_sizes, int n_in,
                              void* d_out, int out_size, void* d_ws, size_t ws_size,
                              hipStream_t stream) {
    const float* query = (const float*)d_in[0];
    const float* key   = (const float*)d_in[1];
    const float* value = (const float*)d_in[2];
    const int*   mask  = (const int*)d_in[3];
    const float* Wq_w  = (const float*)d_in[4];
    const float* Wq_b  = (const float*)d_in[5];
    const float* Wk_w  = (const float*)d_in[6];
    const float* Wk_b  = (const float*)d_in[7];
    float* out = (float*)d_out;

    const size_t BLD = (size_t)B_ * L_ * D_;
    short* qb = (short*)d_ws;
    short* kb = qb + BLD;
    short* vt = kb + BLD;
    _Float16* part = (_Float16*)(vt + BLD);
    float* lpart = (float*)(part + 3 * BLD);

    proj_kernel<<<dim3(256, 2), 256, 0, stream>>>(query, key, Wq_w, Wk_w, Wq_b, Wk_b, qb, kb);
    vtrans_kernel<<<dim3(64, 8), 256, 0, stream>>>(value, vt);
    flash_kernel<<<dim3(8, 32, 4), 256, 0, stream>>>(qb, kb, vt, mask, out, part, lpart);
    norm_kernel<<<dim3((B_ * L_ * D_ / 4) / 256), 256, 0, stream>>>(out, part, lpart);
}